// Round 9
// baseline (174.212 us; speedup 1.0000x reference)
//
#include <hip/hip_runtime.h>
#include <hip/hip_bf16.h>

#define NROWS 16384
#define DIM 64
#define BCOLS 512                  // B tile: 512 cols x 64 k = 64 KB, staged ONCE
#define BROWS 1024                 // 8 waves x 4 si x 32 rows  (R4-exact)
#define NCS (NROWS / BCOLS)        // 32
#define NRG (NROWS / BROWS)        // 16
#define NBLK (NRG * NCS)           // 512 = exactly 2 blocks/CU

static constexpr float TAU = 0.28f;
static constexpr float EPS = 1e-8f;
static constexpr float EXP2_SCALE = (float)(1.0 / (0.28 * 0.6931471805599453));
static constexpr float LN2F = 0.69314718055994530942f;
// Schraudolph exp2: exp2(x) ~= as_float((uint)(x*2^23 + (127-c)*2^23)), c=0.035
// max rel err +-3.6% -> <=0.036 abs on the log-term, threshold is 0.199.
static constexpr float SCH_A = 8388608.0f;          // 2^23
static constexpr float SCH_B = 1.06505962e9f;       // (127 - 0.035) * 2^23

using short8 = __attribute__((ext_vector_type(8))) short;
using f32x4  = __attribute__((ext_vector_type(4))) float;

typedef __attribute__((address_space(1))) const unsigned char ga_t;
typedef __attribute__((address_space(3))) unsigned char la_t;

// Kernel 1: per-row L2 normalize; A = bf16(EXP2_SCALE*u_norm),
// W = bf16(u_norm+i_norm), p[n] = dot/TAU; zero the ticket.
__global__ __launch_bounds__(256) void prep_kernel(
    const float* __restrict__ u, const float* __restrict__ v,
    __hip_bfloat16* __restrict__ a_out, __hip_bfloat16* __restrict__ w_out,
    float* __restrict__ p_out, int* __restrict__ ticket)
{
    const int lane = threadIdx.x & 63;
    const int wv   = threadIdx.x >> 6;
    const int row  = blockIdx.x * 4 + wv;

    const float uu = u[row * DIM + lane];
    const float ii = v[row * DIM + lane];
    float su = uu * uu, si = ii * ii, sd = uu * ii;
#pragma unroll
    for (int m = 1; m < 64; m <<= 1) {
        su += __shfl_xor(su, m, 64);
        si += __shfl_xor(si, m, 64);
        sd += __shfl_xor(sd, m, 64);
    }
    const float inv_u = 1.0f / fmaxf(sqrtf(su), 1e-12f);
    const float inv_i = 1.0f / fmaxf(sqrtf(si), 1e-12f);
    const float un = uu * inv_u;
    const float in = ii * inv_i;
    a_out[row * DIM + lane] = __float2bfloat16(EXP2_SCALE * un);
    w_out[row * DIM + lane] = __float2bfloat16(un + in);
    if (lane == 0) p_out[row] = sd * inv_u * inv_i * (1.0f / TAU);
    if (blockIdx.x == 0 && threadIdx.x == 0) ticket[0] = 0;
}

// Kernel 2: R4-exact structure (512 thr, 64 KB tile staged ONCE, one
// barrier, si=4 x rs=2, ct unroll 8, 512 blocks = 2/CU). Changes vs R4:
// (1) v_exp_f32 -> Schraudolph bit-trick exp2 (3 full-rate VALU ops,
//     frees the transcendental port; error bounded well under threshold);
// (2) contended atomicAdd -> plain stores to pbuf[row][cs] partials.
__global__ __launch_bounds__(512, 4) void score_kernel(
    const __hip_bfloat16* __restrict__ A, const __hip_bfloat16* __restrict__ W,
    float* __restrict__ pbuf, const float* __restrict__ p,
    int* __restrict__ ticket, float* __restrict__ out)
{
    __shared__ alignas(16) ushort blds[BCOLS * DIM];   // 64 KB

    const int tid  = threadIdx.x;
    const int lane = tid & 63;
    const int wv   = tid >> 6;          // 0..7
    const int l15  = lane & 15;
    const int quad = lane >> 4;
    const int cs   = blockIdx.x & (NCS - 1);
    const int rg   = blockIdx.x >> 5;
    const int col0    = cs * BCOLS;
    const int rowbase = rg * BROWS;

    const ushort* Au = (const ushort*)A;
    const ushort* Wu = (const ushort*)W;

    // Stage B ONCE: 4096 16-B chunks, 8/thread; XOR-swizzled (0 conflicts
    // measured R4-R8).
#pragma unroll
    for (int q = 0; q < 8; q++) {
        const int pp = q * 512 + tid;
        const int j  = pp >> 3;
        const int c  = (pp & 7) ^ (j & 7);
        const ushort* g = Wu + (size_t)(col0 + j) * DIM + c * 8;
        __builtin_amdgcn_global_load_lds((ga_t*)g, (la_t*)&blds[(size_t)pp * 8], 16, 0, 0);
    }
    __syncthreads();

    for (int si = 0; si < 4; si++) {
        const int r0 = rowbase + wv * 128 + si * 32;

        short8 af[2][2];
#pragma unroll
        for (int rs = 0; rs < 2; rs++)
#pragma unroll
            for (int kk = 0; kk < 2; kk++)
                af[rs][kk] = *(const short8*)(
                    Au + (size_t)(r0 + rs * 16 + l15) * DIM + kk * 32 + quad * 8);

        float rowsum[2][4];
#pragma unroll
        for (int rs = 0; rs < 2; rs++)
#pragma unroll
            for (int r = 0; r < 4; r++) rowsum[rs][r] = 0.0f;

#pragma unroll 8
        for (int ct = 0; ct < BCOLS / 16; ct++) {
            const int jl = ct * 16 + l15;
            const int sw = l15 & 7;     // == jl & 7
            const short8 b0 = *(const short8*)&blds[(size_t)(jl * 8 + (quad ^ sw)) * 8];
            const short8 b1 = *(const short8*)&blds[(size_t)(jl * 8 + ((4 + quad) ^ sw)) * 8];
#pragma unroll
            for (int rs = 0; rs < 2; rs++) {
                f32x4 acc = {0.f, 0.f, 0.f, 0.f};
                acc = __builtin_amdgcn_mfma_f32_16x16x32_bf16(af[rs][0], b0, acc, 0, 0, 0);
                acc = __builtin_amdgcn_mfma_f32_16x16x32_bf16(af[rs][1], b1, acc, 0, 0, 0);
#pragma unroll
                for (int r = 0; r < 4; r++) {
                    const float t = __builtin_fmaf(acc[r], SCH_A, SCH_B);
                    rowsum[rs][r] += __uint_as_float((unsigned int)t);
                }
            }
        }

        // Sum over the 16 columns held by each l15-group.
#pragma unroll
        for (int m = 1; m < 16; m <<= 1)
#pragma unroll
            for (int rs = 0; rs < 2; rs++)
#pragma unroll
                for (int r = 0; r < 4; r++)
                    rowsum[rs][r] += __shfl_xor(rowsum[rs][r], m, 64);

        if (l15 == 0) {
#pragma unroll
            for (int rs = 0; rs < 2; rs++)
#pragma unroll
                for (int r = 0; r < 4; r++)
                    pbuf[(size_t)(r0 + rs * 16 + quad * 4 + r) * NCS + cs] = rowsum[rs][r];
        }
    }

    // Last block finalizes (device-scope fences; pattern verified R5-R8).
    __shared__ int lastflag;
    __syncthreads();
    if (tid == 0) {
        __threadfence();
        lastflag = (atomicAdd(ticket, 1) == NBLK - 1);
    }
    __syncthreads();
    if (lastflag) {
        __threadfence();
        __shared__ float red[8];
        float s = 0.0f;
        for (int r = tid; r < NROWS; r += 512) {
            const float4* q4 = (const float4*)&pbuf[(size_t)r * NCS];
            float tr = 0.0f;
#pragma unroll
            for (int k = 0; k < NCS / 4; k++) {
                const float4 f = q4[k];
                tr += (f.x + f.y) + (f.z + f.w);
            }
            s += __log2f(tr + EPS) * LN2F - p[r];
        }
#pragma unroll
        for (int m = 1; m < 64; m <<= 1) s += __shfl_xor(s, m, 64);
        if ((tid & 63) == 0) red[tid >> 6] = s;
        __syncthreads();
        if (tid == 0) {
            float t = 0.0f;
#pragma unroll
            for (int k = 0; k < 8; k++) t += red[k];
            out[0] = t * (1.0f / (float)NROWS);
        }
    }
}

extern "C" void kernel_launch(void* const* d_in, const int* in_sizes, int n_in,
                              void* d_out, int out_size, void* d_ws, size_t ws_size,
                              hipStream_t stream) {
    const float* u = (const float*)d_in[0];
    const float* v = (const float*)d_in[1];

    char* ws = (char*)d_ws;
    __hip_bfloat16* a = (__hip_bfloat16*)(ws);                                  // 2 MB
    __hip_bfloat16* w = (__hip_bfloat16*)(ws + (size_t)NROWS * DIM * 2);        // 2 MB
    float* p    = (float*)(ws + (size_t)NROWS * DIM * 4);                       // 64 KB
    float* pbuf = (float*)(ws + (size_t)NROWS * DIM * 4 + (size_t)NROWS * 4);   // 2 MB
    int*   tick = (int*)  (ws + (size_t)NROWS * DIM * 4 + (size_t)NROWS * 4
                              + (size_t)NROWS * NCS * 4);                       // 4 B

    prep_kernel<<<NROWS / 4, 256, 0, stream>>>(u, v, a, w, p, tick);
    score_kernel<<<NBLK, 512, 0, stream>>>(a, w, pbuf, p, tick, (float*)d_out);
}